// Round 9
// baseline (9179.855 us; speedup 1.0000x reference)
//
#include <hip/hip_runtime.h>
#include <hip/hip_bf16.h>
#include <math.h>

#define B 64
#define T 2048
#define D 128
#define H 256
#define G 1024

#define NSL 16            // slices per batch-group
#define NB 4              // batches per group
#define NG 16             // batch-groups
#define L0_U4 3072        // 32 kb * 6 kp * 16 cg  (uint4)
#define L1_U4 4096        // 32 kb * 8 kp * 16 cg
#define SL_U4 (L0_U4 + L1_U4)        // 7168 uint4 per slice
#define SL_UINTS (SL_U4 * 4)         // 28672

typedef _Float16 h2v __attribute__((ext_vector_type(2)));
typedef float f2v __attribute__((ext_vector_type(2)));
typedef unsigned int u4v __attribute__((ext_vector_type(4)));

#if defined(__has_builtin)
#if __has_builtin(__builtin_amdgcn_fdot2)
#define HAS_FDOT2 1
#endif
#endif

__device__ __forceinline__ float dot2(unsigned int w, unsigned int h, float acc) {
#ifdef HAS_FDOT2
    return __builtin_amdgcn_fdot2(__builtin_bit_cast(h2v, w), __builtin_bit_cast(h2v, h), acc, false);
#else
    h2v wv = __builtin_bit_cast(h2v, w);
    h2v hv = __builtin_bit_cast(h2v, h);
    acc = fmaf((float)wv.x, (float)hv.x, acc);
    return fmaf((float)wv.y, (float)hv.y, acc);
#endif
}

__device__ __forceinline__ unsigned short f2h(float f) {
    _Float16 h = (_Float16)f;
    return __builtin_bit_cast(unsigned short, h);
}
__device__ __forceinline__ float h2f(unsigned short u) {
    return (float)__builtin_bit_cast(_Float16, u);
}
__device__ __forceinline__ unsigned int packh2(float a, float b) {
    return (unsigned int)f2h(a) | ((unsigned int)f2h(b) << 16);
}
__device__ __forceinline__ float sigm(float x) { return 1.0f / (1.0f + __expf(-x)); }
__device__ __forceinline__ float ftanh(float x) {
    x = fminf(fmaxf(x, -15.0f), 15.0f);
    float e = __expf(2.0f * x);
    return (e - 1.0f) / (e + 1.0f);
}

// 16 dot2: weight uint4 (4 cols) x h uint4 (4 batches) -> 4x float4 accums
#define DOTB(w_, h_) \
    A0.x=dot2(w_.x,h_.x,A0.x); A0.y=dot2(w_.x,h_.y,A0.y); A0.z=dot2(w_.x,h_.z,A0.z); A0.w=dot2(w_.x,h_.w,A0.w); \
    A1.x=dot2(w_.y,h_.x,A1.x); A1.y=dot2(w_.y,h_.y,A1.y); A1.z=dot2(w_.y,h_.z,A1.z); A1.w=dot2(w_.y,h_.w,A1.w); \
    A2.x=dot2(w_.z,h_.x,A2.x); A2.y=dot2(w_.z,h_.y,A2.y); A2.z=dot2(w_.z,h_.z,A2.z); A2.w=dot2(w_.z,h_.w,A2.w); \
    A3.x=dot2(w_.w,h_.x,A3.x); A3.y=dot2(w_.w,h_.y,A3.y); A3.z=dot2(w_.w,h_.z,A3.z); A3.w=dot2(w_.w,h_.w,A3.w);

// butterfly-sum over the 4 kb-sub lanes (lane^16, lane^32)
#define RED4(A) \
    A.x += __shfl_xor(A.x, 16); A.y += __shfl_xor(A.y, 16); A.z += __shfl_xor(A.z, 16); A.w += __shfl_xor(A.w, 16); \
    A.x += __shfl_xor(A.x, 32); A.y += __shfl_xor(A.y, 32); A.z += __shfl_xor(A.z, 32); A.w += __shfl_xor(A.w, 32);

// ---------------- prep ----------------
__global__ void k_zero(unsigned int* p, int n) {
    int i = blockIdx.x * blockDim.x + threadIdx.x;
    if (i < n) p[i] = 0u;
}

__global__ void k_bias_sum(const float* __restrict__ a, const float* __restrict__ b,
                           float* __restrict__ out, int n) {
    int i = blockIdx.x * blockDim.x + threadIdx.x;
    if (i < n) out[i] = a[i] + b[i];
}

// pack f32 weights -> f16 pairs, per-slice layout:
// L0: [kb 32][kp 6][cg 16] uint4, element e = col cg*4+e, kpair kb*6+kp
// L1: [kb 32][kp 8][cg 16] uint4, kpair kb*8+kp
// col c in [0,64): gate g4 = c>>4, unit u = c&15; row = g4*256 + s*16 + u
__global__ void k_pack_w(const float* __restrict__ Wih0, const float* __restrict__ Whh0,
                         const float* __restrict__ Wih1, const float* __restrict__ Whh1,
                         unsigned int* __restrict__ PW) {
    int idx = blockIdx.x * blockDim.x + threadIdx.x;
    if (idx >= NSL * SL_UINTS) return;
    int s = idx / SL_UINTS;
    int rem = idx % SL_UINTS;
    float v0, v1;
    if (rem < L0_U4 * 4) {
        int q4 = rem >> 2, e = rem & 3;
        int kb = q4 / 96; int r = q4 % 96; int kp = r >> 4; int cg = r & 15;
        int c = cg * 4 + e; int g4 = c >> 4; int u = c & 15;
        int row = g4 * 256 + s * 16 + u;
        int k = (kb * 6 + kp) * 2;
        if (k < 128) { v0 = Wih0[(size_t)row * 128 + k];         v1 = Wih0[(size_t)row * 128 + k + 1]; }
        else         { v0 = Whh0[(size_t)row * 256 + (k - 128)]; v1 = Whh0[(size_t)row * 256 + (k - 127)]; }
    } else {
        int rem2 = rem - L0_U4 * 4;
        int q4 = rem2 >> 2, e = rem2 & 3;
        int kb = q4 / 128; int r = q4 % 128; int kp = r >> 4; int cg = r & 15;
        int c = cg * 4 + e; int g4 = c >> 4; int u = c & 15;
        int row = g4 * 256 + s * 16 + u;
        int k = (kb * 8 + kp) * 2;
        if (k < 256) { v0 = Wih1[(size_t)row * 256 + k];         v1 = Wih1[(size_t)row * 256 + k + 1]; }
        else         { v0 = Whh1[(size_t)row * 256 + (k - 256)]; v1 = Whh1[(size_t)row * 256 + (k - 255)]; }
    }
    PW[idx] = packh2(v0, v1);
}

// ---------------- LDS-resident split LSTM ----------------
// 256 WGs: g = bid&15 (batch group of 4), s = bid>>4 (slice of 16 units/layer).
// Weights: 112 KB in LDS, loaded once -> zero steady-state weight streaming.
// Exchange: 64-uint packed h-slices through L3 (relaxed agent atomics),
// 16 producer flags polled by 16 waves. seqo: [B][T/8][H] x uint4 (8 f16).
__global__ __launch_bounds__(1024) void k_lstm_split(
    const float* __restrict__ x,        // B x T x D (f32)
    const uint4* __restrict__ PW2,
    const float* __restrict__ bs0,      // G
    const float* __restrict__ bs1,      // G
    unsigned int* __restrict__ hxg,     // 2 x NG x NSL x 64 uints
    unsigned int* __restrict__ flags,   // NG x NSL x 64 uints (256B lines)
    unsigned int* __restrict__ seqo)    // B x T/8 x H x 4 uints
{
    __shared__ uint4 wl[SL_U4];              // 114688 B
    __shared__ float s_gacc[8][512];         // 16384 B
    __shared__ float s_g[512];               // 2048 B
    __shared__ unsigned int s_k0p[768];      // [kp 192][b 4]: x kp 0..63 | h0 kp 64..191
    __shared__ unsigned int s_k1p[1024];     // [kp 256][b 4]: h0 kp 0..127 | h1 kp 128..255

    const int g   = blockIdx.x & 15;
    const int s   = blockIdx.x >> 4;
    const int tid = threadIdx.x;
    const int lane = tid & 63;
    const int wv   = tid >> 6;          // wave 0..15
    const int cg   = lane & 15;         // col-group (4 cols)
    const int kbs  = lane >> 4;         // kb-sub 0..3

    // load weight slice into LDS (once)
    {
        const uint4* PWs = PW2 + (size_t)s * SL_U4;
        for (int i = tid; i < SL_U4; i += 1024) wl[i] = PWs[i];
    }

    float bi0 = 0.f, bi1 = 0.f, bi2 = 0.f, bi3 = 0.f;
    if (tid < 64) {
        int u = tid >> 2;
        bi0 = bs0[s * 16 + u]; bi1 = bs0[256 + s * 16 + u];
        bi2 = bs0[512 + s * 16 + u]; bi3 = bs0[768 + s * 16 + u];
    } else if (tid < 128) {
        int u = (tid - 64) >> 2;
        bi0 = bs1[s * 16 + u]; bi1 = bs1[256 + s * 16 + u];
        bi2 = bs1[512 + s * 16 + u]; bi3 = bs1[768 + s * 16 + u];
    }
    float c0 = 0.f, c1 = 0.f;
    unsigned int hb0 = 0u, hb1 = 0u, hb2 = 0u, hb3 = 0u;   // 8-step h1 batch

    // prologue: zero h sections, stage x(0)
    if (tid < 512) s_k0p[256 + tid] = 0u;
    s_k1p[tid] = 0u;
    if (tid >= 512 && tid < 768) {
        int i = tid - 512; int b = i >> 6; int kp = i & 63;
        f2v v = __builtin_nontemporal_load((const f2v*)(x + (size_t)(g * NB + b) * T * D) + kp);
        s_k0p[kp * 4 + b] = packh2(v.x, v.y);
    }

    for (int t = 0; ; ++t) {
        __syncthreads();                               // A: staging + weights visible

        // ---- gemm: waves 0-7 = L0 (K=192 kp), waves 8-15 = L1 (K=256 kp) ----
        if (wv < 8) {
            if (t < T) {
                int kb = wv * 4 + kbs;                 // 0..31
                const uint4* wp = wl + (size_t)(kb * 6) * 16 + cg;
                float4 A0 = make_float4(0.f,0.f,0.f,0.f), A1 = A0, A2 = A0, A3 = A0;
                #pragma unroll
                for (int kp = 0; kp < 6; ++kp) {
                    uint4 w = wp[kp * 16];
                    uint4 h = *(const uint4*)&s_k0p[(kb * 6 + kp) * 4];
                    DOTB(w, h);
                }
                RED4(A0); RED4(A1); RED4(A2); RED4(A3);
                if (kbs == 0) {
                    *(float4*)&s_gacc[wv][cg * 16 + 0]  = A0;
                    *(float4*)&s_gacc[wv][cg * 16 + 4]  = A1;
                    *(float4*)&s_gacc[wv][cg * 16 + 8]  = A2;
                    *(float4*)&s_gacc[wv][cg * 16 + 12] = A3;
                }
            }
        } else {
            int kb = (wv - 8) * 4 + kbs;               // 0..31
            const uint4* wp = wl + L0_U4 + (size_t)(kb * 8) * 16 + cg;
            float4 A0 = make_float4(0.f,0.f,0.f,0.f), A1 = A0, A2 = A0, A3 = A0;
            #pragma unroll
            for (int kp = 0; kp < 8; ++kp) {
                uint4 w = wp[kp * 16];
                uint4 h = *(const uint4*)&s_k1p[(kb * 8 + kp) * 4];
                DOTB(w, h);
            }
            RED4(A0); RED4(A1); RED4(A2); RED4(A3);
            if (kbs == 0) {
                *(float4*)&s_gacc[wv - 8][256 + cg * 16 + 0]  = A0;
                *(float4*)&s_gacc[wv - 8][256 + cg * 16 + 4]  = A1;
                *(float4*)&s_gacc[wv - 8][256 + cg * 16 + 8]  = A2;
                *(float4*)&s_gacc[wv - 8][256 + cg * 16 + 12] = A3;
            }
        }
        __syncthreads();                               // B

        if (tid < 512) {
            float sum = s_gacc[0][tid] + s_gacc[1][tid] + s_gacc[2][tid] + s_gacc[3][tid]
                      + s_gacc[4][tid] + s_gacc[5][tid] + s_gacc[6][tid] + s_gacc[7][tid];
            s_g[tid] = sum;
        }
        __syncthreads();                               // C

        // ---- owners + x prefetch ----
        if (tid < 64) {            // L0 unit (s*16 + u), batch g*4+b
            if (t < T) {
                int u = tid >> 2, b = tid & 3;
                float gi = s_g[u * 4 + b]          + bi0;
                float gf = s_g[(16 + u) * 4 + b]   + bi1;
                float gg = s_g[(32 + u) * 4 + b]   + bi2;
                float go = s_g[(48 + u) * 4 + b]   + bi3;
                c0 = sigm(gf) * c0 + sigm(gi) * ftanh(gg);
                float h0v = sigm(go) * ftanh(c0);
                float other = __shfl_xor(h0v, 4);
                if ((u & 1) == 0) {
                    size_t off = (((size_t)(t & 1) * NG + g) * NSL + s) * 64 + (u >> 1) * 4 + b;
                    __hip_atomic_store(hxg + off, packh2(h0v, other),
                                       __ATOMIC_RELAXED, __HIP_MEMORY_SCOPE_AGENT);
                }
            }
        } else if (tid < 128) {    // L1 unit -> h1(t-1)
            int u = (tid - 64) >> 2, b = tid & 3;
            float h1v = 0.0f;
            if (t >= 1) {
                float gi = s_g[256 + u * 4 + b]        + bi0;
                float gf = s_g[256 + (16 + u) * 4 + b] + bi1;
                float gg = s_g[256 + (32 + u) * 4 + b] + bi2;
                float go = s_g[256 + (48 + u) * 4 + b] + bi3;
                c1 = sigm(gf) * c1 + sigm(gi) * ftanh(gg);
                h1v = sigm(go) * ftanh(c1);
                unsigned int hv = (unsigned int)f2h(h1v);
                int st = (t - 1) & 7;
                switch (st) {
                    case 0: hb0 = hv; break;
                    case 1: hb0 |= hv << 16; break;
                    case 2: hb1 = hv; break;
                    case 3: hb1 |= hv << 16; break;
                    case 4: hb2 = hv; break;
                    case 5: hb2 |= hv << 16; break;
                    case 6: hb3 = hv; break;
                    default: hb3 |= hv << 16; break;
                }
                if (st == 7) {
                    size_t idx = ((size_t)(g * NB + b) * (T / 8) + ((t - 1) >> 3)) * H + (s * 16 + u);
                    u4v val = {hb0, hb1, hb2, hb3};
                    __builtin_nontemporal_store(val, (u4v*)(seqo + idx * 4));
                }
            }
            if (t < T) {
                float other = __shfl_xor(h1v, 4);
                if ((u & 1) == 0) {
                    size_t off = (((size_t)(t & 1) * NG + g) * NSL + s) * 64 + 32 + (u >> 1) * 4 + b;
                    __hip_atomic_store(hxg + off, packh2(h1v, other),
                                       __ATOMIC_RELAXED, __HIP_MEMORY_SCOPE_AGENT);
                }
            }
        } else if (tid >= 512 && tid < 768) {
            if (t + 1 < T) {
                int i = tid - 512; int b = i >> 6; int kp = i & 63;
                f2v v = __builtin_nontemporal_load(
                    (const f2v*)(x + (size_t)(g * NB + b) * T * D) + (size_t)(t + 1) * 64 + kp);
                s_k0p[kp * 4 + b] = packh2(v.x, v.y);
            }
        }

        if (t == T) break;                             // uniform exit

        __syncthreads();                               // D1: stores drained (vmcnt0 at barrier)

        if (tid == 0) {
            __hip_atomic_store(flags + ((size_t)g * NSL + s) * 64, (unsigned)(t + 1),
                               __ATOMIC_RELAXED, __HIP_MEMORY_SCOPE_AGENT);
        }

        // ---- wave wv polls slice wv, reads its 64-uint h-slice, stages ----
        {
            unsigned f = 0;
            const unsigned int* fp = flags + ((size_t)g * NSL + wv) * 64;
            do {
                if (lane == 0) f = __hip_atomic_load(fp, __ATOMIC_RELAXED, __HIP_MEMORY_SCOPE_AGENT);
                f = __shfl(f, 0);
                if (f < (unsigned)(t + 1)) __builtin_amdgcn_s_sleep(1);
            } while (f < (unsigned)(t + 1));
            unsigned v = __hip_atomic_load(
                hxg + (((size_t)(t & 1) * NG + g) * NSL + wv) * 64 + lane,
                __ATOMIC_RELAXED, __HIP_MEMORY_SCOPE_AGENT);
            int layer = lane >> 5, kp_loc = (lane >> 2) & 7, b = lane & 3;
            int kpg = wv * 8 + kp_loc;
            if (layer == 0) {
                s_k0p[(64 + kpg) * 4 + b] = v;
                s_k1p[kpg * 4 + b] = v;
            } else {
                s_k1p[(128 + kpg) * 4 + b] = v;
            }
        }
    }
}

// ---------------- attention (seqo: [B][T/8][H] x uint4 = 8 f16) ----------------
__global__ __launch_bounds__(256) void k_a2(const unsigned int* __restrict__ seq,
                                            const float* __restrict__ W2,
                                            float* __restrict__ a2out)
{
    __shared__ float s_hT[H];
    int b = blockIdx.x;
    int k = threadIdx.x;
    unsigned v = seq[(((size_t)b * (T / 8) + 255) * H + k) * 4 + 3];
    s_hT[k] = h2f((unsigned short)(v >> 16));
    __syncthreads();
    float acc = 0.f;
    #pragma unroll 4
    for (int h = 0; h < H; ++h) acc += s_hT[h] * W2[h * H + k];
    a2out[b * H + k] = acc;
}

__global__ __launch_bounds__(256) void k_scores(const unsigned int* __restrict__ seq,
                                                const float* __restrict__ W1,
                                                const float* __restrict__ a2,
                                                const float* __restrict__ attn_w,
                                                float* __restrict__ scores)
{
    const int RPB = 32;
    __shared__ float s_rows[RPB][H];
    __shared__ float s_part[RPB][4];
    int b   = blockIdx.y;
    int t0  = blockIdx.x * RPB;
    int tid = threadIdx.x;

    for (int it = tid; it < 4 * H; it += 256) {
        int tgi = it >> 8, h = it & 255;
        uint4 v = ((const uint4*)seq)[((size_t)b * (T / 8) + (t0 >> 3) + tgi) * H + h];
        int r0 = tgi * 8;
        s_rows[r0 + 0][h] = h2f((unsigned short)v.x);
        s_rows[r0 + 1][h] = h2f((unsigned short)(v.x >> 16));
        s_rows[r0 + 2][h] = h2f((unsigned short)v.y);
        s_rows[r0 + 3][h] = h2f((unsigned short)(v.y >> 16));
        s_rows[r0 + 4][h] = h2f((unsigned short)v.z);
        s_rows[r0 + 5][h] = h2f((unsigned short)(v.z >> 16));
        s_rows[r0 + 6][h] = h2f((unsigned short)v.w);
        s_rows[r0 + 7][h] = h2f((unsigned short)(v.w >> 16));
    }
    __syncthreads();

    int c = tid;
    float acc[RPB];
    #pragma unroll
    for (int r = 0; r < RPB; ++r) acc[r] = 0.f;
    for (int h = 0; h < H; ++h) {
        float w = W1[h * H + c];
        #pragma unroll
        for (int r = 0; r < RPB; ++r) acc[r] += s_rows[r][h] * w;
    }
    float a2v = a2[b * H + c];
    float wc  = attn_w[c];
    int lane = tid & 63, wv = tid >> 6;
    #pragma unroll
    for (int r = 0; r < RPB; ++r) {
        float v = ftanh(acc[r] + a2v) * wc;
        for (int off = 32; off; off >>= 1) v += __shfl_down(v, off);
        if (lane == 0) s_part[r][wv] = v;
    }
    __syncthreads();
    if (tid < RPB) {
        scores[(size_t)b * T + t0 + tid] =
            s_part[tid][0] + s_part[tid][1] + s_part[tid][2] + s_part[tid][3];
    }
}

__global__ __launch_bounds__(256) void k_finish(const unsigned int* __restrict__ seq,
                                                const float* __restrict__ scores,
                                                const float* __restrict__ gamma,
                                                const float* __restrict__ beta,
                                                float* __restrict__ out)
{
    __shared__ float s_p[T];
    __shared__ float s_red[4];
    const int b = blockIdx.x;
    const int tid = threadIdx.x;
    const int lane = tid & 63, wv = tid >> 6;

    const float* sc = scores + (size_t)b * T;
    float m = -1e30f;
    for (int t = tid; t < T; t += 256) m = fmaxf(m, sc[t]);
    for (int off = 32; off; off >>= 1) m = fmaxf(m, __shfl_down(m, off));
    if (lane == 0) s_red[wv] = m;
    __syncthreads();
    m = fmaxf(fmaxf(s_red[0], s_red[1]), fmaxf(s_red[2], s_red[3]));
    __syncthreads();

    float z = 0.f;
    for (int t = tid; t < T; t += 256) { float e = __expf(sc[t] - m); s_p[t] = e; z += e; }
    for (int off = 32; off; off >>= 1) z += __shfl_down(z, off);
    if (lane == 0) s_red[wv] = z;
    __syncthreads();
    z = s_red[0] + s_red[1] + s_red[2] + s_red[3];
    float rz = 1.0f / z;
    __syncthreads();

    const uint4* sq = (const uint4*)seq + (size_t)b * (T / 8) * H + tid;
    float ctx = 0.f;
    for (int tg = 0; tg < T / 8; ++tg) {
        uint4 v = sq[(size_t)tg * H];
        const float* pp = &s_p[tg * 8];
        ctx += pp[0] * h2f((unsigned short)v.x) + pp[1] * h2f((unsigned short)(v.x >> 16))
             + pp[2] * h2f((unsigned short)v.y) + pp[3] * h2f((unsigned short)(v.y >> 16))
             + pp[4] * h2f((unsigned short)v.z) + pp[5] * h2f((unsigned short)(v.z >> 16))
             + pp[6] * h2f((unsigned short)v.w) + pp[7] * h2f((unsigned short)(v.w >> 16));
    }
    ctx *= rz;

    float s1 = ctx;
    for (int off = 32; off; off >>= 1) s1 += __shfl_down(s1, off);
    if (lane == 0) s_red[wv] = s1;
    __syncthreads();
    float mu = (s_red[0] + s_red[1] + s_red[2] + s_red[3]) * (1.0f / H);
    __syncthreads();
    float dv = ctx - mu;
    float s2 = dv * dv;
    for (int off = 32; off; off >>= 1) s2 += __shfl_down(s2, off);
    if (lane == 0) s_red[wv] = s2;
    __syncthreads();
    float var = (s_red[0] + s_red[1] + s_red[2] + s_red[3]) * (1.0f / H);
    out[b * H + tid] = dv * rsqrtf(var + 1e-5f) * gamma[tid] + beta[tid];
}

// ---------------- host ----------------
extern "C" void kernel_launch(void* const* d_in, const int* in_sizes, int n_in,
                              void* d_out, int out_size, void* d_ws, size_t ws_size,
                              hipStream_t stream) {
    const float* x     = (const float*)d_in[0];
    const float* Wih0  = (const float*)d_in[1];
    const float* Whh0  = (const float*)d_in[2];
    const float* bih0  = (const float*)d_in[3];
    const float* bhh0  = (const float*)d_in[4];
    const float* Wih1  = (const float*)d_in[5];
    const float* Whh1  = (const float*)d_in[6];
    const float* bih1  = (const float*)d_in[7];
    const float* bhh1  = (const float*)d_in[8];
    const float* aW1   = (const float*)d_in[9];
    const float* aW2   = (const float*)d_in[10];
    const float* aw    = (const float*)d_in[11];
    const float* gamma = (const float*)d_in[12];
    const float* beta  = (const float*)d_in[13];
    float* out = (float*)d_out;

    // ---- workspace layout (bytes), ~66.5 MB ----
    char* base = (char*)d_ws;
    unsigned int* PW    = (unsigned int*)(base);            // 1,835,008 B (16 slices x 28672 uints)
    float* bsum0        = (float*)(base + 1835008);         // 4096 B
    float* bsum1        = (float*)(base + 1839104);         // 4096 B
    unsigned int* flags = (unsigned int*)(base + 1843200);  // 65,536 B (16x16 x 256B lines)
    unsigned int* hxg   = (unsigned int*)(base + 1908736);  // 131,072 B (2x16x16x64 uints)
    float* a2buf        = (float*)(base + 2039808);         // 65,536 B
    float* scoresb      = (float*)(base + 2105344);         // 524,288 B
    unsigned int* seqo  = (unsigned int*)(base + 2629632);  // 67,108,864 B

    k_zero<<<(NG * NSL * 64 + 255) / 256, 256, 0, stream>>>(flags, NG * NSL * 64);
    k_pack_w<<<(NSL * SL_UINTS) / 256, 256, 0, stream>>>(Wih0, Whh0, Wih1, Whh1, PW);
    k_bias_sum<<<(G + 255) / 256, 256, 0, stream>>>(bih0, bhh0, bsum0, G);
    k_bias_sum<<<(G + 255) / 256, 256, 0, stream>>>(bih1, bhh1, bsum1, G);

    k_lstm_split<<<256, 1024, 0, stream>>>(x, (const uint4*)PW, bsum0, bsum1, hxg, flags, seqo);

    k_a2<<<B, H, 0, stream>>>(seqo, aW2, a2buf);
    k_scores<<<dim3(T / 32, B), 256, 0, stream>>>(seqo, aW1, a2buf, aw, scoresb);
    k_finish<<<B, 256, 0, stream>>>(seqo, scoresb, gamma, beta, out);
}